// Round 13
// baseline (435.917 us; speedup 1.0000x reference)
//
#include <hip/hip_runtime.h>
#include <hip/hip_bf16.h>
#include <cstdint>

// ---------------------------------------------------------------------------
// WorldModel RSSM: B=1024 T=50 E=1024 A=6 S=200 H=200 L=30
// fp32 in/out; internal GEMMs bf16 MFMA w/ fp32 accum.
//
//   k1: GI[bt,0:600]=concat(a,e)@W_ih+b_ih ; GI[bt,600:800]=e@Wq1[200:]+bq1
//       tile 128x400 (A staged only 2x -> total staged 1.05GB), 16 waves,
//       wave = 1M x 13N (52 AGPR), counted-vmcnt 2-deep pipeline, A
//       reg->bf16->LDS (T14 split). launch_bounds(1024,4): 4 waves/SIMD.
//   k2: GRU scan, 64 blocks x 8 waves, W_hh resident in regs (round 7).
//   k3: heads, 32 rows/block: each Wpq frag feeds 2 MFMAs (L2 traffic /2).
// ---------------------------------------------------------------------------

typedef __attribute__((ext_vector_type(8))) short   short8;
typedef __attribute__((ext_vector_type(8))) __bf16  bf16x8;
typedef __attribute__((ext_vector_type(4))) float   f32x4;

__device__ __forceinline__ float bf2f(unsigned short u) {
    unsigned int v = ((unsigned int)u) << 16;
    return __builtin_bit_cast(float, v);
}
__device__ __forceinline__ unsigned short f2bf(float f) {
    unsigned int v = __builtin_bit_cast(unsigned int, f);
    v = v + 0x7FFFu + ((v >> 16) & 1u);   // RNE
    return (unsigned short)(v >> 16);
}
__device__ __forceinline__ float softplusf(float x) {
    return (x > 20.f) ? x : log1pf(__expf(x));
}
__device__ __forceinline__ void gload_lds16(const void* g, void* l) {
    __builtin_amdgcn_global_load_lds(
        (const __attribute__((address_space(1))) void*)g,
        (__attribute__((address_space(3))) void*)l, 16, 0, 0);
}

// ---------------- workspace layout (bytes) ----------------
#define OFF_BPACK 81920000
#define OFF_WHH   83558400
#define OFF_WPQ1  83837952
#define OFF_WPQ2  84024320

// fragment mapping (mfma_f32_16x16x32_bf16):
//   A[l&15][(l>>4)*8+j], B[(l>>4)*8+j][l&15], D[(l>>4)*4+r][l&15]
// packed B storage: elem = ((kk*NT + nt)*64 + l)*8 + j

__global__ __launch_bounds__(256) void pack_kernel(
    const float* __restrict__ W_ih, const float* __restrict__ W_hh,
    const float* __restrict__ Wp1,  const float* __restrict__ Wq1,
    const float* __restrict__ Wp2,  const float* __restrict__ Wq2,
    unsigned short* __restrict__ Bpack, unsigned short* __restrict__ Whh_p,
    unsigned short* __restrict__ Wpq1,  unsigned short* __restrict__ Wpq2)
{
    int e = blockIdx.x * 256 + threadIdx.x;
    if (e < 819200) {                       // k1: K=1024(embed), N=800
        const int j = e & 7, l = (e >> 3) & 63;
        const int nt = (e >> 9) % 50, kk = e / (512 * 50);
        const int k = kk * 32 + (l >> 4) * 8 + j;
        const int c = nt * 16 + (l & 15);
        Bpack[e] = f2bf((c < 600) ? W_ih[(6 + k) * 600 + c]
                                  : Wq1[(200 + k) * 200 + (c - 600)]);
        return;
    }
    e -= 819200;
    if (e < 139776) {                       // W_hh: K pad 224, N = 3 gates x 13 tiles
        const int j = e & 7, l = (e >> 3) & 63;
        const int nt = (e >> 9) % 39, kk = e / (512 * 39);
        const int k = kk * 32 + (l >> 4) * 8 + j;
        const int g = nt / 13, st = nt % 13;
        const int c = st * 16 + (l & 15);
        Whh_p[e] = (k < 200 && c < 200) ? f2bf(W_hh[k * 600 + g * 200 + c]) : (unsigned short)0;
        return;
    }
    e -= 139776;
    if (e < 93184) {                        // heads1: [Wp1 | Wq1[:200]] K pad 224
        const int j = e & 7, l = (e >> 3) & 63;
        const int nt = (e >> 9) % 26, kk = e / (512 * 26);
        const int k = kk * 32 + (l >> 4) * 8 + j;
        unsigned short v = 0;
        if (nt < 13) { const int c = nt * 16 + (l & 15);        if (k < 200 && c < 200) v = f2bf(Wp1[k * 200 + c]); }
        else         { const int c = (nt - 13) * 16 + (l & 15); if (k < 200 && c < 200) v = f2bf(Wq1[k * 200 + c]); }
        Wpq1[e] = v;
        return;
    }
    e -= 93184;
    if (e < 28672) {                        // heads2: [Wp2 | Wq2] N pad 64 each
        const int j = e & 7, l = (e >> 3) & 63;
        const int nt = (e >> 9) % 8, kk = e / (512 * 8);
        const int k = kk * 32 + (l >> 4) * 8 + j;
        unsigned short v = 0;
        if (nt < 4) { const int c = nt * 16 + (l & 15);       if (k < 200 && c < 60) v = f2bf(Wp2[k * 60 + c]); }
        else        { const int c = (nt - 4) * 16 + (l & 15); if (k < 200 && c < 60) v = f2bf(Wq2[k * 60 + c]); }
        Wpq2[e] = v;
    }
}

// ---------------- kernel 1: GI/QE GEMM  M=51200 N=800 K=1024 ----------------
// grid 800 = 400 M-chunks(128 rows) x 2 N-halves(400 cols = 25 tiles).
// 1024 thr = 16 waves; wave w: A subtile w>>1, N-half w&1 -> 13/12 N-tiles.
// Buffer (bytes): [0,25600) B 25 tiles (gload_lds); [25600,33792) A bf16
// fragment-order (reg-staged cvt, ds_write_b64/thread). Counted-vmcnt:
// {A-load -> fence -> B-DMA -> vmcnt(1+nB) -> bar -> MFMA -> vmcnt(nB) ->
//  cvt+ds_write -> lgkm(0) -> bar}; never drains to 0 in-loop.
#define K1_BYTES 33792
#define K1_AOFF  25600
__global__ __launch_bounds__(1024, 4) void k1_gi(
    const float* __restrict__ embed,   // [51200][1024]
    const float* __restrict__ action,  // [51200][6]
    const float* __restrict__ W_ih,    // rows 0..5 = action part
    const float* __restrict__ b_ih,
    const float* __restrict__ bq1,
    const unsigned short* __restrict__ Bpack,
    unsigned short* __restrict__ GI)   // [51200][800] bf16
{
    __shared__ char bufS[2][K1_BYTES];

    const int tid = threadIdx.x;
    const int w = tid >> 6, l = tid & 63;
    const int lo = l & 15, hi = l >> 4;

    // pair-preserving XCD swizzle (800 = 8 XCD x 100): both N-halves of an
    // M-chunk land on the same XCD -> shared A lines in that XCD's L2.
    const int gsw  = (blockIdx.x & 7) * 100 + (blockIdx.x >> 3);
    const int mblk = gsw >> 1;
    const int ng   = gsw & 1;
    const int rb   = mblk * 128;

    // ---- B stage chunks: wave w stages tiles {w, w+16} ∩ [0,25)
    const char* bsp[2]; int bdof[2];
    const int nB = (w < 9) ? 2 : 1;
#pragma unroll
    for (int i = 0; i < 2; ++i) {
        int j = w + 16 * i; if (j >= 25) j = 24;
        bsp[i]  = (const char*)Bpack + (size_t)(ng * 25 + j) * 1024 + l * 16;
        bdof[i] = j * 1024;
    }

    // ---- A reg-stage: thread -> (ms 0..7, la 0..63, half 0..1), one dwordx4
    const int ms  = tid >> 7;
    const int la  = (tid & 127) >> 1;
    const int hf2 = tid & 1;
    const float* aSrc = embed + (size_t)(rb + ms * 16 + (la & 15)) * 1024
                      + (la >> 4) * 8 + hf2 * 4;
    const int awo = K1_AOFF + ms * 1024 + la * 16 + hf2 * 8;

    // ---- MFMA mapping
    const int msw = w >> 1;                // A subtile
    const int nq  = w & 1;
    const int nn  = nq ? 12 : 13;
    const int tb  = nq * 13;

    f32x4 acc[13];
#pragma unroll
    for (int i = 0; i < 13; ++i) acc[i] = f32x4{0.f, 0.f, 0.f, 0.f};

    // ---- prologue: A(0) regs + B(0) DMA; cvt+write buf0 A
    {
        f32x4 a0 = *(const f32x4*)aSrc;
        __builtin_amdgcn_sched_barrier(0);
#pragma unroll
        for (int i = 0; i < 2; ++i) if (i < nB) {
            gload_lds16(bsp[i], &bufS[0][bdof[i]]);
            bsp[i] += 51200;
        }
        if (w < 9) asm volatile("s_waitcnt vmcnt(2)" ::: "memory");
        else       asm volatile("s_waitcnt vmcnt(1)" ::: "memory");
        __builtin_amdgcn_sched_barrier(0);
        unsigned long long v =
              (unsigned long long)f2bf(a0[0])
            | ((unsigned long long)f2bf(a0[1]) << 16)
            | ((unsigned long long)f2bf(a0[2]) << 32)
            | ((unsigned long long)f2bf(a0[3]) << 48);
        *(unsigned long long*)&bufS[0][awo] = v;
    }
    asm volatile("s_waitcnt lgkmcnt(0)" ::: "memory");

    // ---- main loop
    int cur = 0;
    for (int kk = 0; kk < 32; ++kk) {
        const int nxt = cur ^ 1;
        f32x4 a1;
        if (kk < 31) {
            a1 = *(const f32x4*)(aSrc + (size_t)(kk + 1) * 32);
            __builtin_amdgcn_sched_barrier(0);
#pragma unroll
            for (int i = 0; i < 2; ++i) if (i < nB) {
                gload_lds16(bsp[i], &bufS[nxt][bdof[i]]);
                bsp[i] += 51200;
            }
            if (w < 9) asm volatile("s_waitcnt vmcnt(3)" ::: "memory");  // drain B(kk)
            else       asm volatile("s_waitcnt vmcnt(2)" ::: "memory");
        } else {
            asm volatile("s_waitcnt vmcnt(0)" ::: "memory");
        }
        __builtin_amdgcn_s_barrier();          // buf cur fully staged
        __builtin_amdgcn_sched_barrier(0);

        // compute from cur: 1 A-frag x 13/12 B-tiles
        bf16x8 af = __builtin_bit_cast(bf16x8,
            *(const short8*)&bufS[cur][K1_AOFF + msw * 1024 + l * 16]);
#pragma unroll
        for (int i = 0; i < 13; ++i) if (i < nn) {
            bf16x8 b = __builtin_bit_cast(bf16x8,
                *(const short8*)&bufS[cur][(tb + i) * 1024 + l * 16]);
            acc[i] = __builtin_amdgcn_mfma_f32_16x16x32_bf16(af, b, acc[i], 0, 0, 0);
        }

        if (kk < 31) {
            if (w < 9) asm volatile("s_waitcnt vmcnt(2)" ::: "memory");  // A(kk+1) regs done
            else       asm volatile("s_waitcnt vmcnt(1)" ::: "memory");
            __builtin_amdgcn_sched_barrier(0);
            unsigned long long v =
                  (unsigned long long)f2bf(a1[0])
                | ((unsigned long long)f2bf(a1[1]) << 16)
                | ((unsigned long long)f2bf(a1[2]) << 32)
                | ((unsigned long long)f2bf(a1[3]) << 48);
            *(unsigned long long*)&bufS[nxt][awo] = v;
        }

        asm volatile("s_waitcnt lgkmcnt(0)" ::: "memory");   // LDS reads+writes done
        __builtin_amdgcn_s_barrier();
        __builtin_amdgcn_sched_barrier(0);
        cur = nxt;
    }

    // ---- epilogue: bias + action(K=6) contribution, store bf16
    {
        const int rbase = rb + msw * 16 + hi * 4;
        float av[4][6];
#pragma unroll
        for (int r = 0; r < 4; ++r)
#pragma unroll
            for (int k = 0; k < 6; ++k) av[r][k] = action[(size_t)(rbase + r) * 6 + k];
#pragma unroll
        for (int i = 0; i < 13; ++i) if (i < nn) {
            const int col = ng * 400 + (tb + i) * 16 + lo;
            const float bias = (col < 600) ? b_ih[col] : bq1[col - 600];
            float wa[6];
            if (col < 600) {
#pragma unroll
                for (int k = 0; k < 6; ++k) wa[k] = W_ih[k * 600 + col];
            }
#pragma unroll
            for (int r = 0; r < 4; ++r) {
                float v = acc[i][r] + bias;
                if (col < 600) {
#pragma unroll
                    for (int k = 0; k < 6; ++k) v += av[r][k] * wa[k];
                }
                GI[(size_t)(rbase + r) * 800 + col] = f2bf(v);
            }
        }
    }
}

// ---------------- kernel 2: GRU scan, 8 waves, resident weights ----------------
#define HSTRB 232   // row stride in bf16 elems (K pad >=224)
#define GSTR  227   // gAll row stride in floats (odd-ish vs 32 banks)

__global__ __launch_bounds__(512, 2) void k2_scan(
    unsigned short* __restrict__ GI,           // [51200][800] bf16 (deter -> cols 0..199)
    const unsigned short* __restrict__ Whh_p,
    const float* __restrict__ b_hh,
    float* __restrict__ out)                   // [51200][350] fp32 (cols 0..199 here)
{
    __shared__ unsigned short hS[16 * HSTRB];                 // 7424 B, bf16 h
    __shared__ float gAll[3 * 16 * GSTR];                     // 43584 B
    __shared__ __align__(16) unsigned short GIbuf[2][12288];  // 49152 B

    const int tid = threadIdx.x;
    const int w = tid >> 6, l = tid & 63;
    const int lo = l & 15, hi = l >> 4;
    const int r0 = blockIdx.x * 16;

    for (int i = tid; i < 16 * HSTRB; i += 512) hS[i] = 0;

    const int t0 = w * 5;
    const int ntl = (w == 7) ? 4 : 5;
    bf16x8 wf[5][7];
#pragma unroll
    for (int i = 0; i < 5; ++i)
#pragma unroll
        for (int kk = 0; kk < 7; ++kk)
            if (i < ntl)
                wf[i][kk] = __builtin_bit_cast(bf16x8,
                    *(const short8*)&Whh_p[((kk * 39 + (t0 + i)) * 64 + l) * 8]);

    int gOff[5];
#pragma unroll
    for (int i = 0; i < 5; ++i) {
        int nt = t0 + i; if (nt > 38) nt = 38;
        const int g = nt / 13, st = nt - g * 13;
        gOff[i] = (g * 16 + hi * 4) * GSTR + st * 16 + lo;
    }

    const char* srcB[3];
#pragma unroll
    for (int i = 0; i < 3; ++i) {
        int j = (i * 8 + w) * 64 + l;
        int rj = j / 75; int cj = j - rj * 75;
        if (rj > 15) { rj = 15; cj = 74; }
        srcB[i] = (const char*)GI + (size_t)(r0 + rj) * 50 * 1600 + (size_t)cj * 16;
    }

    const int c = tid & 255;
    const int rh = tid >> 8;
    const bool act = (c < 200);
    float bh0 = 0.f, bh1 = 0.f, bh2 = 0.f;
    if (act) { bh0 = b_hh[c]; bh1 = b_hh[200 + c]; bh2 = b_hh[400 + c]; }
    float h_reg[8] = {0.f, 0.f, 0.f, 0.f, 0.f, 0.f, 0.f, 0.f};

    {
#pragma unroll
        for (int i = 0; i < 3; ++i)
            gload_lds16(srcB[i], &GIbuf[0][(i * 8 + w) * 512]);
    }
    asm volatile("s_waitcnt lgkmcnt(0)" ::: "memory");
    __builtin_amdgcn_s_barrier();
    __builtin_amdgcn_sched_barrier(0);

    for (int t = 0; t < 50; ++t) {
        const int tn = (t < 49) ? t + 1 : 49;
        const int bsel = (t + 1) & 1;
#pragma unroll
        for (int i = 0; i < 3; ++i)
            gload_lds16(srcB[i] + (size_t)tn * 1600, &GIbuf[bsel][(i * 8 + w) * 512]);

        bf16x8 hf[7];
#pragma unroll
        for (int kk = 0; kk < 7; ++kk)
            hf[kk] = __builtin_bit_cast(bf16x8,
                *(const short8*)&hS[lo * HSTRB + kk * 32 + hi * 8]);
        f32x4 acc[5];
#pragma unroll
        for (int i = 0; i < 5; ++i) acc[i] = f32x4{0.f, 0.f, 0.f, 0.f};
#pragma unroll
        for (int i = 0; i < 5; ++i) if (i < ntl)
#pragma unroll
            for (int kk = 0; kk < 7; ++kk)
                acc[i] = __builtin_amdgcn_mfma_f32_16x16x32_bf16(hf[kk], wf[i][kk], acc[i], 0, 0, 0);

#pragma unroll
        for (int i = 0; i < 5; ++i) if (i < ntl)
#pragma unroll
            for (int r = 0; r < 4; ++r)
                gAll[gOff[i] + r * GSTR] = acc[i][r];

        asm volatile("s_waitcnt lgkmcnt(0)" ::: "memory");   // B1
        __builtin_amdgcn_s_barrier();
        __builtin_amdgcn_sched_barrier(0);
        asm volatile("s_waitcnt vmcnt(3)" ::: "memory");     // GIbuf[t&1] ready
        __builtin_amdgcn_sched_barrier(0);

        if (act) {
            const unsigned short* gib = &GIbuf[t & 1][0];
#pragma unroll
            for (int rr = 0; rr < 8; ++rr) {
                const int row = rh * 8 + rr;
                const float gi_r = bf2f(gib[row * 600 + c]);
                const float gi_z = bf2f(gib[row * 600 + 200 + c]);
                const float gi_n = bf2f(gib[row * 600 + 400 + c]);
                const float gr = gi_r + gAll[(0 * 16 + row) * GSTR + c] + bh0;
                const float gz = gi_z + gAll[(1 * 16 + row) * GSTR + c] + bh1;
                const float hn = gAll[(2 * 16 + row) * GSTR + c] + bh2;
                const float rs = __builtin_amdgcn_rcpf(1.f + __expf(-gr));
                const float zz = __builtin_amdgcn_rcpf(1.f + __expf(-gz));
                const float x  = gi_n + rs * hn;
                const float e2 = __expf(-2.f * fabsf(x));
                float th = (1.f - e2) * __builtin_amdgcn_rcpf(1.f + e2);
                th = __builtin_copysignf(th, x);
                const float h = (1.f - zz) * th + zz * h_reg[rr];
                h_reg[rr] = h;
                hS[row * HSTRB + c] = f2bf(h);
                const size_t bt = (size_t)((r0 + row) * 50 + t);
                out[bt * 350 + c] = h;                 // deter fp32
                GI[bt * 800 + c]  = f2bf(h);           // deter bf16 for k3
            }
        }

        asm volatile("s_waitcnt lgkmcnt(0)" ::: "memory");   // B2
        __builtin_amdgcn_s_barrier();
        __builtin_amdgcn_sched_barrier(0);
    }
}

// ---------------- kernel 3: heads, 32 rows/block (Wpq frag feeds 2 MFMAs) ----
__global__ __launch_bounds__(256, 1) void k3_heads(
    const unsigned short* __restrict__ GI,     // deter bf16 cols 0..199, QE cols 600..799
    const unsigned short* __restrict__ Wpq1,
    const unsigned short* __restrict__ Wpq2,
    const float* __restrict__ noise,           // [51200][30]
    const float* __restrict__ bp1,
    const float* __restrict__ bp2,
    const float* __restrict__ bq2,
    float* __restrict__ out)                   // cols 200..349
{
    __shared__ unsigned short pq[2][32 * HSTRB];  // elu prior/post h1, 32 rows
    __shared__ float ost[32 * 128];               // pm|ps|qm|qs raw

    const int tid = threadIdx.x;
    const int w = tid >> 6, l = tid & 63;
    const int lo = l & 15, hi = l >> 4;
    const int r0 = blockIdx.x * 32;

    {   unsigned short* p0 = &pq[0][0];
        for (int i = tid; i < 2 * 32 * HSTRB; i += 256) p0[i] = 0; }
    __syncthreads();

    // A-fragments: deter for 2 row-groups (K pad 200..223 garbage x B-zero = safe)
    bf16x8 af[2][7];
#pragma unroll
    for (int rg = 0; rg < 2; ++rg)
#pragma unroll
        for (int kk = 0; kk < 7; ++kk)
            af[rg][kk] = __builtin_bit_cast(bf16x8,
                *(const short8*)&GI[(size_t)(r0 + rg * 16 + lo) * 800 + kk * 32 + hi * 8]);

    // heads1: 26 N-tiles over 4 waves (7/7/6/6); each B frag -> 2 MFMAs
    const int h1s = (w < 2) ? 7 * w : 14 + 6 * (w - 2);
    const int h1n = (w < 2) ? 7 : 6;
    f32x4 a2[2][7];
#pragma unroll
    for (int rg = 0; rg < 2; ++rg)
#pragma unroll
        for (int i = 0; i < 7; ++i) a2[rg][i] = f32x4{0.f, 0.f, 0.f, 0.f};
#pragma unroll
    for (int i = 0; i < 7; ++i) if (i < h1n) {
        const int nt = h1s + i;
#pragma unroll
        for (int kk = 0; kk < 7; ++kk) {
            bf16x8 b = __builtin_bit_cast(bf16x8,
                *(const short8*)&Wpq1[((kk * 26 + nt) * 64 + l) * 8]);
            a2[0][i] = __builtin_amdgcn_mfma_f32_16x16x32_bf16(af[0][kk], b, a2[0][i], 0, 0, 0);
            a2[1][i] = __builtin_amdgcn_mfma_f32_16x16x32_bf16(af[1][kk], b, a2[1][i], 0, 0, 0);
        }
    }
#pragma unroll
    for (int i = 0; i < 7; ++i) if (i < h1n) {
        const int nt = h1s + i;
        const bool isq = (nt >= 13);
        const int c1 = (isq ? (nt - 13) : nt) * 16 + lo;
        if (c1 < 200) {
#pragma unroll
            for (int rg = 0; rg < 2; ++rg)
#pragma unroll
                for (int r = 0; r < 4; ++r) {
                    const int lrow = rg * 16 + hi * 4 + r;
                    float v = a2[rg][i][r];
                    if (isq) v += bf2f(GI[(size_t)(r0 + lrow) * 800 + 600 + c1]);  // QE (incl bq1)
                    else     v += bp1[c1];
                    v = (v > 0.f) ? v : expm1f(v);                                  // ELU
                    pq[isq ? 1 : 0][lrow * HSTRB + c1] = f2bf(v);
                }
        }
    }
    __syncthreads();

    // heads2: waves 0,1 -> prior; waves 2,3 -> posterior; 2 row-groups each
    const unsigned short* srcS = &pq[(w >= 2) ? 1 : 0][0];
    bf16x8 pf[2][7];
#pragma unroll
    for (int rg = 0; rg < 2; ++rg)
#pragma unroll
        for (int kk = 0; kk < 7; ++kk)
            pf[rg][kk] = __builtin_bit_cast(bf16x8,
                *(const short8*)&srcS[(rg * 16 + lo) * HSTRB + kk * 32 + hi * 8]);
    f32x4 a3[2][2];
#pragma unroll
    for (int rg = 0; rg < 2; ++rg) {
        a3[rg][0] = f32x4{0.f, 0.f, 0.f, 0.f};
        a3[rg][1] = f32x4{0.f, 0.f, 0.f, 0.f};
    }
#pragma unroll
    for (int i = 0; i < 2; ++i) {
        const int nt = ((w >= 2) ? 4 : 0) + (w & 1) * 2 + i;
#pragma unroll
        for (int kk = 0; kk < 7; ++kk) {
            bf16x8 b = __builtin_bit_cast(bf16x8,
                *(const short8*)&Wpq2[((kk * 8 + nt) * 64 + l) * 8]);
            a3[0][i] = __builtin_amdgcn_mfma_f32_16x16x32_bf16(pf[0][kk], b, a3[0][i], 0, 0, 0);
            a3[1][i] = __builtin_amdgcn_mfma_f32_16x16x32_bf16(pf[1][kk], b, a3[1][i], 0, 0, 0);
        }
    }
#pragma unroll
    for (int i = 0; i < 2; ++i) {
        const int nt = ((w >= 2) ? 4 : 0) + (w & 1) * 2 + i;
        const int cl = (nt & 3) * 16 + lo;
        if (cl < 60) {
            const float bb = (nt < 4) ? bp2[cl] : bq2[cl];
            const int obase = ((nt < 4) ? 0 : 64) + ((cl < 30) ? cl : (32 + cl - 30));
#pragma unroll
            for (int rg = 0; rg < 2; ++rg)
#pragma unroll
                for (int r = 0; r < 4; ++r)
                    ost[(rg * 16 + hi * 4 + r) * 128 + obase] = a3[rg][i][r] + bb;
        }
    }
    __syncthreads();

    // pack cols 200..349 for 32 rows
    for (int idx = tid; idx < 32 * 150; idx += 256) {
        const int row = idx / 150;
        const int c = 200 + (idx - row * 150);
        const size_t bt = (size_t)(r0 + row);
        const float* o = &ost[row * 128];
        float v;
        if (c < 230) {
            const int j = c - 200;
            const float qs = softplusf(o[96 + j]) + 0.1f;
            v = o[64 + j] + qs * noise[bt * 30 + j];
        }
        else if (c < 260) v = o[c - 230];
        else if (c < 290) v = softplusf(o[32 + (c - 260)]) + 0.1f;
        else if (c < 320) v = o[64 + (c - 290)];
        else              v = softplusf(o[96 + (c - 320)]) + 0.1f;
        out[bt * 350 + c] = v;
    }
}

// ---------------------------------------------------------------------------
extern "C" void kernel_launch(void* const* d_in, const int* in_sizes, int n_in,
                              void* d_out, int out_size, void* d_ws, size_t ws_size,
                              hipStream_t stream)
{
    const float* action = (const float*)d_in[0];
    const float* embed  = (const float*)d_in[1];
    const float* noise  = (const float*)d_in[2];
    const float* W_ih   = (const float*)d_in[3];
    const float* W_hh   = (const float*)d_in[4];
    const float* b_ih   = (const float*)d_in[5];
    const float* b_hh   = (const float*)d_in[6];
    const float* Wp1    = (const float*)d_in[7];
    const float* bp1    = (const float*)d_in[8];
    const float* Wp2    = (const float*)d_in[9];
    const float* bp2    = (const float*)d_in[10];
    const float* Wq1    = (const float*)d_in[11];
    const float* bq1    = (const float*)d_in[12];
    const float* Wq2    = (const float*)d_in[13];
    const float* bq2    = (const float*)d_in[14];
    (void)in_sizes; (void)n_in; (void)out_size; (void)ws_size;

    char* ws = (char*)d_ws;
    unsigned short* GI    = (unsigned short*)(ws);
    unsigned short* Bpack = (unsigned short*)(ws + OFF_BPACK);
    unsigned short* Whh_p = (unsigned short*)(ws + OFF_WHH);
    unsigned short* Wpq1  = (unsigned short*)(ws + OFF_WPQ1);
    unsigned short* Wpq2  = (unsigned short*)(ws + OFF_WPQ2);
    float* outp = (float*)d_out;

    pack_kernel<<<4222, 256, 0, stream>>>(W_ih, W_hh, Wp1, Wq1, Wp2, Wq2,
                                          Bpack, Whh_p, Wpq1, Wpq2);
    k1_gi<<<800, 1024, 0, stream>>>(embed, action, W_ih, b_ih, bq1, Bpack, GI);
    k2_scan<<<64, 512, 0, stream>>>(GI, Whh_p, b_hh, outp);
    k3_heads<<<1600, 256, 0, stream>>>(GI, Wpq1, Wpq2, noise, bp1, bp2, bq2, outp);
}

// Round 14
// 429.112 us; speedup vs baseline: 1.0159x; 1.0159x over previous
//
#include <hip/hip_runtime.h>
#include <hip/hip_bf16.h>
#include <cstdint>

// ---------------------------------------------------------------------------
// WorldModel RSSM: B=1024 T=50 E=1024 A=6 S=200 H=200 L=30
// fp32 in/out; internal GEMMs bf16 MFMA w/ fp32 accum.
//
//   k1: GI[bt,0:600]=concat(a,e)@W_ih+b_ih ; GI[bt,600:800]=e@Wq1[200:]+bq1
//       round-10 skeleton (128x160, 4 waves, counted vmcnt, 2 bar/iter) but
//       A operand NEVER touches LDS: per-lane HBM->reg, 2-deep prefetch,
//       cvt in-reg (no cross-wave A reuse -> LDS round-trip was pure cost).
//       LDS = B-only 2x10KB. 3 blocks/CU.
//   k2: GRU scan, 64 blocks x 8 waves, W_hh resident in regs (round 7).
//   k3: heads, 16 rows/block, 3200 blocks (round-10 version).
// ---------------------------------------------------------------------------

typedef __attribute__((ext_vector_type(8))) short   short8;
typedef __attribute__((ext_vector_type(8))) __bf16  bf16x8;
typedef __attribute__((ext_vector_type(4))) float   f32x4;

__device__ __forceinline__ float bf2f(unsigned short u) {
    unsigned int v = ((unsigned int)u) << 16;
    return __builtin_bit_cast(float, v);
}
__device__ __forceinline__ unsigned short f2bf(float f) {
    unsigned int v = __builtin_bit_cast(unsigned int, f);
    v = v + 0x7FFFu + ((v >> 16) & 1u);   // RNE
    return (unsigned short)(v >> 16);
}
__device__ __forceinline__ float softplusf(float x) {
    return (x > 20.f) ? x : log1pf(__expf(x));
}
__device__ __forceinline__ void gload_lds16(const void* g, void* l) {
    __builtin_amdgcn_global_load_lds(
        (const __attribute__((address_space(1))) void*)g,
        (__attribute__((address_space(3))) void*)l, 16, 0, 0);
}

// ---------------- workspace layout (bytes) ----------------
#define OFF_BPACK 81920000
#define OFF_WHH   83558400
#define OFF_WPQ1  83837952
#define OFF_WPQ2  84024320

// fragment mapping (mfma_f32_16x16x32_bf16):
//   A[l&15][(l>>4)*8+j], B[(l>>4)*8+j][l&15], D[(l>>4)*4+r][l&15]
// packed B storage: elem = ((kk*NT + nt)*64 + l)*8 + j

__global__ __launch_bounds__(256) void pack_kernel(
    const float* __restrict__ W_ih, const float* __restrict__ W_hh,
    const float* __restrict__ Wp1,  const float* __restrict__ Wq1,
    const float* __restrict__ Wp2,  const float* __restrict__ Wq2,
    unsigned short* __restrict__ Bpack, unsigned short* __restrict__ Whh_p,
    unsigned short* __restrict__ Wpq1,  unsigned short* __restrict__ Wpq2)
{
    int e = blockIdx.x * 256 + threadIdx.x;
    if (e < 819200) {                       // k1: K=1024(embed), N=800
        const int j = e & 7, l = (e >> 3) & 63;
        const int nt = (e >> 9) % 50, kk = e / (512 * 50);
        const int k = kk * 32 + (l >> 4) * 8 + j;
        const int c = nt * 16 + (l & 15);
        Bpack[e] = f2bf((c < 600) ? W_ih[(6 + k) * 600 + c]
                                  : Wq1[(200 + k) * 200 + (c - 600)]);
        return;
    }
    e -= 819200;
    if (e < 139776) {                       // W_hh: K pad 224, N = 3 gates x 13 tiles
        const int j = e & 7, l = (e >> 3) & 63;
        const int nt = (e >> 9) % 39, kk = e / (512 * 39);
        const int k = kk * 32 + (l >> 4) * 8 + j;
        const int g = nt / 13, st = nt % 13;
        const int c = st * 16 + (l & 15);
        Whh_p[e] = (k < 200 && c < 200) ? f2bf(W_hh[k * 600 + g * 200 + c]) : (unsigned short)0;
        return;
    }
    e -= 139776;
    if (e < 93184) {                        // heads1: [Wp1 | Wq1[:200]] K pad 224
        const int j = e & 7, l = (e >> 3) & 63;
        const int nt = (e >> 9) % 26, kk = e / (512 * 26);
        const int k = kk * 32 + (l >> 4) * 8 + j;
        unsigned short v = 0;
        if (nt < 13) { const int c = nt * 16 + (l & 15);        if (k < 200 && c < 200) v = f2bf(Wp1[k * 200 + c]); }
        else         { const int c = (nt - 13) * 16 + (l & 15); if (k < 200 && c < 200) v = f2bf(Wq1[k * 200 + c]); }
        Wpq1[e] = v;
        return;
    }
    e -= 93184;
    if (e < 28672) {                        // heads2: [Wp2 | Wq2] N pad 64 each
        const int j = e & 7, l = (e >> 3) & 63;
        const int nt = (e >> 9) % 8, kk = e / (512 * 8);
        const int k = kk * 32 + (l >> 4) * 8 + j;
        unsigned short v = 0;
        if (nt < 4) { const int c = nt * 16 + (l & 15);       if (k < 200 && c < 60) v = f2bf(Wp2[k * 60 + c]); }
        else        { const int c = (nt - 4) * 16 + (l & 15); if (k < 200 && c < 60) v = f2bf(Wq2[k * 60 + c]); }
        Wpq2[e] = v;
    }
}

// ---------------- kernel 1: GI/QE GEMM  M=51200 N=800 K=1024 ----------------
// grid 2000 = 400 M-chunks(128 rows) x 5 N-groups(160 cols = 10 tiles).
// 256 thr = 4 waves; wave w -> M-subtiles {2w,2w+1} x all 10 N-tiles
// (acc[2][10] = 80 AGPR). LDS = B only, 2 x 10KB dbuf (gload_lds).
// A: per-lane HBM->reg (dense 128B/row/iter), 2-deep prefetch, cvt in-reg.
// Per-iter: {A(kk+1) reg-loads -> fence -> B(kk+1) DMA -> vmcnt(4+nB)
//  [A(kk),B(kk) proven done] -> bar -> cvt+MFMA -> lgkm(0) -> bar}.
#define K1_BYTES 10240
__global__ __launch_bounds__(256, 3) void k1_gi(
    const float* __restrict__ embed,   // [51200][1024]
    const float* __restrict__ action,  // [51200][6]
    const float* __restrict__ W_ih,    // rows 0..5 = action part
    const float* __restrict__ b_ih,
    const float* __restrict__ bq1,
    const unsigned short* __restrict__ Bpack,
    unsigned short* __restrict__ GI)   // [51200][800] bf16
{
    __shared__ char bufS[2][K1_BYTES];

    const int tid = threadIdx.x;
    const int w = tid >> 6, l = tid & 63;
    const int lo = l & 15, hi = l >> 4;

    // XCD-bijective swizzle: 5 N-siblings of an M-chunk land on one XCD
    const int g    = (blockIdx.x & 7) * 250 + (blockIdx.x >> 3);
    const int mblk = g / 5;
    const int ng   = g - mblk * 5;
    const int rb   = mblk * 128;

    // ---- B stage chunks: wave w covers j = w + 4i < 10 (w<2: 3, else 2)
    const char* bsp[3]; int bdof[3];
    const int nB = (w < 2) ? 3 : 2;
#pragma unroll
    for (int i = 0; i < 3; ++i) {
        int j = w + 4 * i; if (j >= 10) j = 9;
        bsp[i]  = (const char*)Bpack + (size_t)(ng * 10 + j) * 1024 + l * 16;
        bdof[i] = j * 1024;
    }

    // ---- A per-lane sources (frag order: row = l&15, k-octet = l>>4)
    const float* aSrc0 = embed + (size_t)(rb + (w * 2 + 0) * 16 + lo) * 1024 + hi * 8;
    const float* aSrc1 = embed + (size_t)(rb + (w * 2 + 1) * 16 + lo) * 1024 + hi * 8;

    f32x4 acc[2][10];
#pragma unroll
    for (int m = 0; m < 2; ++m)
#pragma unroll
        for (int i = 0; i < 10; ++i) acc[m][i] = f32x4{0.f, 0.f, 0.f, 0.f};

    // ---- prologue: A(0) regs + B(0) DMA (no wait here)
    f32x4 c0a = *(const f32x4*)(aSrc0);
    f32x4 c0b = *(const f32x4*)(aSrc0 + 4);
    f32x4 c1a = *(const f32x4*)(aSrc1);
    f32x4 c1b = *(const f32x4*)(aSrc1 + 4);
    __builtin_amdgcn_sched_barrier(0);
#pragma unroll
    for (int i = 0; i < 3; ++i) if (i < nB) {
        gload_lds16(bsp[i], &bufS[0][bdof[i]]);
        bsp[i] += 51200;
    }

    // ---- main loop
    int cur = 0;
    for (int kk = 0; kk < 32; ++kk) {
        const int nxt = cur ^ 1;
        f32x4 n0a, n0b, n1a, n1b;
        if (kk < 31) {
            const float* p0 = aSrc0 + (size_t)(kk + 1) * 32;
            const float* p1 = aSrc1 + (size_t)(kk + 1) * 32;
            n0a = *(const f32x4*)(p0);
            n0b = *(const f32x4*)(p0 + 4);
            n1a = *(const f32x4*)(p1);
            n1b = *(const f32x4*)(p1 + 4);
            __builtin_amdgcn_sched_barrier(0);
#pragma unroll
            for (int i = 0; i < 3; ++i) if (i < nB) {
                gload_lds16(bsp[i], &bufS[nxt][bdof[i]]);
                bsp[i] += 51200;
            }
            // wait: A(kk)+B(kk) done; A(kk+1)(4)+B(kk+1)(nB) stay in flight
            if (w < 2) asm volatile("s_waitcnt vmcnt(7)" ::: "memory");
            else       asm volatile("s_waitcnt vmcnt(6)" ::: "memory");
        } else {
            asm volatile("s_waitcnt vmcnt(0)" ::: "memory");
        }
        __builtin_amdgcn_s_barrier();          // B(kk) staged for all waves
        __builtin_amdgcn_sched_barrier(0);

        // cvt A(kk) in-reg, then MFMA over 10 B-tiles x 2 M-subs
        bf16x8 af0, af1;
#pragma unroll
        for (int q = 0; q < 4; ++q) {
            af0[q] = (__bf16)c0a[q]; af0[4 + q] = (__bf16)c0b[q];
            af1[q] = (__bf16)c1a[q]; af1[4 + q] = (__bf16)c1b[q];
        }
#pragma unroll
        for (int i = 0; i < 10; ++i) {
            bf16x8 b = __builtin_bit_cast(bf16x8,
                *(const short8*)&bufS[cur][i * 1024 + l * 16]);
            acc[0][i] = __builtin_amdgcn_mfma_f32_16x16x32_bf16(af0, b, acc[0][i], 0, 0, 0);
            acc[1][i] = __builtin_amdgcn_mfma_f32_16x16x32_bf16(af1, b, acc[1][i], 0, 0, 0);
        }

        asm volatile("s_waitcnt lgkmcnt(0)" ::: "memory");   // all B reads done
        __builtin_amdgcn_s_barrier();          // buf cur may be overwritten next
        __builtin_amdgcn_sched_barrier(0);

        c0a = n0a; c0b = n0b; c1a = n1a; c1b = n1b;
        cur = nxt;
    }

    // ---- epilogue: bias + action(K=6) contribution, store bf16
#pragma unroll
    for (int m = 0; m < 2; ++m) {
        const int rbase = rb + (w * 2 + m) * 16 + hi * 4;
        float av[4][6];
#pragma unroll
        for (int r = 0; r < 4; ++r)
#pragma unroll
            for (int k = 0; k < 6; ++k) av[r][k] = action[(size_t)(rbase + r) * 6 + k];
#pragma unroll
        for (int i = 0; i < 10; ++i) {
            const int col = ng * 160 + i * 16 + lo;
            const float bias = (col < 600) ? b_ih[col] : bq1[col - 600];
            float wa[6];
            if (col < 600) {
#pragma unroll
                for (int k = 0; k < 6; ++k) wa[k] = W_ih[k * 600 + col];
            }
#pragma unroll
            for (int r = 0; r < 4; ++r) {
                float v = acc[m][i][r] + bias;
                if (col < 600) {
#pragma unroll
                    for (int k = 0; k < 6; ++k) v += av[r][k] * wa[k];
                }
                GI[(size_t)(rbase + r) * 800 + col] = f2bf(v);
            }
        }
    }
}

// ---------------- kernel 2: GRU scan, 8 waves, resident weights ----------------
#define HSTRB 232   // hS row stride in bf16 elems (K pad >=224)
#define GSTR  227   // gAll row stride in floats (odd-ish vs 32 banks)

__global__ __launch_bounds__(512, 2) void k2_scan(
    unsigned short* __restrict__ GI,           // [51200][800] bf16 (deter -> cols 0..199)
    const unsigned short* __restrict__ Whh_p,
    const float* __restrict__ b_hh,
    float* __restrict__ out)                   // [51200][350] fp32 (cols 0..199 here)
{
    __shared__ unsigned short hS[16 * HSTRB];                 // 7424 B, bf16 h
    __shared__ float gAll[3 * 16 * GSTR];                     // 43584 B
    __shared__ __align__(16) unsigned short GIbuf[2][12288];  // 49152 B

    const int tid = threadIdx.x;
    const int w = tid >> 6, l = tid & 63;
    const int lo = l & 15, hi = l >> 4;
    const int r0 = blockIdx.x * 16;

    for (int i = tid; i < 16 * HSTRB; i += 512) hS[i] = 0;

    const int t0 = w * 5;
    const int ntl = (w == 7) ? 4 : 5;
    bf16x8 wf[5][7];
#pragma unroll
    for (int i = 0; i < 5; ++i)
#pragma unroll
        for (int kk = 0; kk < 7; ++kk)
            if (i < ntl)
                wf[i][kk] = __builtin_bit_cast(bf16x8,
                    *(const short8*)&Whh_p[((kk * 39 + (t0 + i)) * 64 + l) * 8]);

    int gOff[5];
#pragma unroll
    for (int i = 0; i < 5; ++i) {
        int nt = t0 + i; if (nt > 38) nt = 38;
        const int g = nt / 13, st = nt - g * 13;
        gOff[i] = (g * 16 + hi * 4) * GSTR + st * 16 + lo;
    }

    const char* srcB[3];
#pragma unroll
    for (int i = 0; i < 3; ++i) {
        int j = (i * 8 + w) * 64 + l;
        int rj = j / 75; int cj = j - rj * 75;
        if (rj > 15) { rj = 15; cj = 74; }
        srcB[i] = (const char*)GI + (size_t)(r0 + rj) * 50 * 1600 + (size_t)cj * 16;
    }

    const int c = tid & 255;
    const int rh = tid >> 8;
    const bool act = (c < 200);
    float bh0 = 0.f, bh1 = 0.f, bh2 = 0.f;
    if (act) { bh0 = b_hh[c]; bh1 = b_hh[200 + c]; bh2 = b_hh[400 + c]; }
    float h_reg[8] = {0.f, 0.f, 0.f, 0.f, 0.f, 0.f, 0.f, 0.f};

    {
#pragma unroll
        for (int i = 0; i < 3; ++i)
            gload_lds16(srcB[i], &GIbuf[0][(i * 8 + w) * 512]);
    }
    asm volatile("s_waitcnt lgkmcnt(0)" ::: "memory");
    __builtin_amdgcn_s_barrier();
    __builtin_amdgcn_sched_barrier(0);

    for (int t = 0; t < 50; ++t) {
        const int tn = (t < 49) ? t + 1 : 49;
        const int bsel = (t + 1) & 1;
#pragma unroll
        for (int i = 0; i < 3; ++i)
            gload_lds16(srcB[i] + (size_t)tn * 1600, &GIbuf[bsel][(i * 8 + w) * 512]);

        bf16x8 hf[7];
#pragma unroll
        for (int kk = 0; kk < 7; ++kk)
            hf[kk] = __builtin_bit_cast(bf16x8,
                *(const short8*)&hS[lo * HSTRB + kk * 32 + hi * 8]);
        f32x4 acc[5];
#pragma unroll
        for (int i = 0; i < 5; ++i) acc[i] = f32x4{0.f, 0.f, 0.f, 0.f};
#pragma unroll
        for (int i = 0; i < 5; ++i) if (i < ntl)
#pragma unroll
            for (int kk = 0; kk < 7; ++kk)
                acc[i] = __builtin_amdgcn_mfma_f32_16x16x32_bf16(hf[kk], wf[i][kk], acc[i], 0, 0, 0);

#pragma unroll
        for (int i = 0; i < 5; ++i) if (i < ntl)
#pragma unroll
            for (int r = 0; r < 4; ++r)
                gAll[gOff[i] + r * GSTR] = acc[i][r];

        asm volatile("s_waitcnt lgkmcnt(0)" ::: "memory");   // B1
        __builtin_amdgcn_s_barrier();
        __builtin_amdgcn_sched_barrier(0);
        asm volatile("s_waitcnt vmcnt(3)" ::: "memory");     // GIbuf[t&1] ready
        __builtin_amdgcn_sched_barrier(0);

        if (act) {
            const unsigned short* gib = &GIbuf[t & 1][0];
#pragma unroll
            for (int rr = 0; rr < 8; ++rr) {
                const int row = rh * 8 + rr;
                const float gi_r = bf2f(gib[row * 600 + c]);
                const float gi_z = bf2f(gib[row * 600 + 200 + c]);
                const float gi_n = bf2f(gib[row * 600 + 400 + c]);
                const float gr = gi_r + gAll[(0 * 16 + row) * GSTR + c] + bh0;
                const float gz = gi_z + gAll[(1 * 16 + row) * GSTR + c] + bh1;
                const float hn = gAll[(2 * 16 + row) * GSTR + c] + bh2;
                const float rs = __builtin_amdgcn_rcpf(1.f + __expf(-gr));
                const float zz = __builtin_amdgcn_rcpf(1.f + __expf(-gz));
                const float x  = gi_n + rs * hn;
                const float e2 = __expf(-2.f * fabsf(x));
                float th = (1.f - e2) * __builtin_amdgcn_rcpf(1.f + e2);
                th = __builtin_copysignf(th, x);
                const float h = (1.f - zz) * th + zz * h_reg[rr];
                h_reg[rr] = h;
                hS[row * HSTRB + c] = f2bf(h);
                const size_t bt = (size_t)((r0 + row) * 50 + t);
                out[bt * 350 + c] = h;                 // deter fp32
                GI[bt * 800 + c]  = f2bf(h);           // deter bf16 for k3
            }
        }

        asm volatile("s_waitcnt lgkmcnt(0)" ::: "memory");   // B2
        __builtin_amdgcn_s_barrier();
        __builtin_amdgcn_sched_barrier(0);
    }
}

// ---------------- kernel 3: heads, fully parallel over 51200 rows ----------------
__global__ __launch_bounds__(256, 1) void k3_heads(
    const unsigned short* __restrict__ GI,     // deter bf16 cols 0..199, QE cols 600..799
    const unsigned short* __restrict__ Wpq1,
    const unsigned short* __restrict__ Wpq2,
    const float* __restrict__ noise,           // [51200][30]
    const float* __restrict__ bp1,
    const float* __restrict__ bp2,
    const float* __restrict__ bq2,
    float* __restrict__ out)                   // cols 200..349
{
    __shared__ unsigned short pq[2][16 * HSTRB];
    __shared__ float ost[16 * 128];

    const int tid = threadIdx.x;
    const int w = tid >> 6, l = tid & 63;
    const int lo = l & 15, hi = l >> 4;
    const int r0 = blockIdx.x * 16;

    {   unsigned short* p0 = &pq[0][0];
        for (int i = tid; i < 2 * 16 * HSTRB; i += 256) p0[i] = 0; }
    __syncthreads();

    bf16x8 af[7];
#pragma unroll
    for (int kk = 0; kk < 7; ++kk)
        af[kk] = __builtin_bit_cast(bf16x8,
            *(const short8*)&GI[(size_t)(r0 + lo) * 800 + kk * 32 + hi * 8]);

    const int h1s = (w < 2) ? 7 * w : 14 + 6 * (w - 2);
    const int h1n = (w < 2) ? 7 : 6;
    f32x4 a2[7];
#pragma unroll
    for (int i = 0; i < 7; ++i) a2[i] = f32x4{0.f, 0.f, 0.f, 0.f};
#pragma unroll
    for (int i = 0; i < 7; ++i) if (i < h1n) {
        const int nt = h1s + i;
#pragma unroll
        for (int kk = 0; kk < 7; ++kk) {
            bf16x8 b = __builtin_bit_cast(bf16x8,
                *(const short8*)&Wpq1[((kk * 26 + nt) * 64 + l) * 8]);
            a2[i] = __builtin_amdgcn_mfma_f32_16x16x32_bf16(af[kk], b, a2[i], 0, 0, 0);
        }
    }
#pragma unroll
    for (int i = 0; i < 7; ++i) if (i < h1n) {
        const int nt = h1s + i;
        const bool isq = (nt >= 13);
        const int c1 = (isq ? (nt - 13) : nt) * 16 + lo;
        if (c1 < 200) {
#pragma unroll
            for (int r = 0; r < 4; ++r) {
                const int row = hi * 4 + r;
                float v = a2[i][r];
                if (isq) v += bf2f(GI[(size_t)(r0 + row) * 800 + 600 + c1]);  // QE (incl bq1)
                else     v += bp1[c1];
                v = (v > 0.f) ? v : expm1f(v);                                 // ELU
                pq[isq ? 1 : 0][row * HSTRB + c1] = f2bf(v);
            }
        }
    }
    __syncthreads();

    const unsigned short* srcS = &pq[(w >= 2) ? 1 : 0][0];
    bf16x8 pf[7];
#pragma unroll
    for (int kk = 0; kk < 7; ++kk)
        pf[kk] = __builtin_bit_cast(bf16x8,
            *(const short8*)&srcS[lo * HSTRB + kk * 32 + hi * 8]);
    f32x4 a3[2];
    a3[0] = f32x4{0.f, 0.f, 0.f, 0.f};
    a3[1] = f32x4{0.f, 0.f, 0.f, 0.f};
#pragma unroll
    for (int i = 0; i < 2; ++i) {
        const int nt = ((w >= 2) ? 4 : 0) + (w & 1) * 2 + i;
#pragma unroll
        for (int kk = 0; kk < 7; ++kk) {
            bf16x8 b = __builtin_bit_cast(bf16x8,
                *(const short8*)&Wpq2[((kk * 8 + nt) * 64 + l) * 8]);
            a3[i] = __builtin_amdgcn_mfma_f32_16x16x32_bf16(pf[kk], b, a3[i], 0, 0, 0);
        }
    }
#pragma unroll
    for (int i = 0; i < 2; ++i) {
        const int nt = ((w >= 2) ? 4 : 0) + (w & 1) * 2 + i;
        const int cl = (nt & 3) * 16 + lo;
        if (cl < 60) {
            const float bb = (nt < 4) ? bp2[cl] : bq2[cl];
            const int obase = ((nt < 4) ? 0 : 64) + ((cl < 30) ? cl : (32 + cl - 30));
#pragma unroll
            for (int r = 0; r < 4; ++r)
                ost[(hi * 4 + r) * 128 + obase] = a3[i][r] + bb;
        }
    }
    __syncthreads();

    for (int idx = tid; idx < 16 * 150; idx += 256) {
        const int row = idx / 150;
        const int c = 200 + (idx - row * 150);
        const size_t bt = (size_t)(r0 + row);
        const float* o = &ost[row * 128];
        float v;
        if (c < 230) {
            const int j = c - 200;
            const float qs = softplusf(o[96 + j]) + 0.1f;
            v = o[64 + j] + qs * noise[bt * 30 + j];
        }
        else if (c < 260) v = o[c - 230];
        else if (c < 290) v = softplusf(o[32 + (c - 260)]) + 0.1f;
        else if (c < 320) v = o[64 + (c - 290)];
        else              v = softplusf(o[96 + (c - 320)]) + 0.1f;
        out[bt * 350 + c] = v;
    }
}

// ---------------------------------------------------------------------------
extern "C" void kernel_launch(void* const* d_in, const int* in_sizes, int n_in,
                              void* d_out, int out_size, void* d_ws, size_t ws_size,
                              hipStream_t stream)
{
    const float* action = (const float*)d_in[0];
    const float* embed  = (const float*)d_in[1];
    const float* noise  = (const float*)d_in[2];
    const float* W_ih   = (const float*)d_in[3];
    const float* W_hh   = (const float*)d_in[4];
    const float* b_ih   = (const float*)d_in[5];
    const float* b_hh   = (const float*)d_in[6];
    const float* Wp1    = (const float*)d_in[7];
    const float* bp1    = (const float*)d_in[8];
    const float* Wp2    = (const float*)d_in[9];
    const float* bp2    = (const float*)d_in[10];
    const float* Wq1    = (const float*)d_in[11];
    const float* bq1    = (const float*)d_in[12];
    const float* Wq2    = (const float*)d_in[13];
    const float* bq2    = (const float*)d_in[14];
    (void)in_sizes; (void)n_in; (void)out_size; (void)ws_size;

    char* ws = (char*)d_ws;
    unsigned short* GI    = (unsigned short*)(ws);
    unsigned short* Bpack = (unsigned short*)(ws + OFF_BPACK);
    unsigned short* Whh_p = (unsigned short*)(ws + OFF_WHH);
    unsigned short* Wpq1  = (unsigned short*)(ws + OFF_WPQ1);
    unsigned short* Wpq2  = (unsigned short*)(ws + OFF_WPQ2);
    float* outp = (float*)d_out;

    pack_kernel<<<4222, 256, 0, stream>>>(W_ih, W_hh, Wp1, Wq1, Wp2, Wq2,
                                          Bpack, Whh_p, Wpq1, Wpq2);
    k1_gi<<<2000, 256, 0, stream>>>(embed, action, W_ih, b_ih, bq1, Bpack, GI);
    k2_scan<<<64, 512, 0, stream>>>(GI, Whh_p, b_hh, outp);
    k3_heads<<<3200, 256, 0, stream>>>(GI, Wpq1, Wpq2, noise, bp1, bp2, bq2, outp);
}

// Round 15
// 368.245 us; speedup vs baseline: 1.1838x; 1.1653x over previous
//
#include <hip/hip_runtime.h>
#include <hip/hip_bf16.h>
#include <cstdint>

// ---------------------------------------------------------------------------
// WorldModel RSSM: B=1024 T=50 E=1024 A=6 S=200 H=200 L=30
// fp32 in/out; internal GEMMs bf16 MFMA w/ fp32 accum.
//
// Session-best configuration (round 10, 368 us total):
//   k1: GI[bt,0:600]=concat(a,e)@W_ih+b_ih ; GI[bt,600:800]=e@Wq1[200:]+bq1
//       128x160 tile, counted-vmcnt 2-deep pipeline, A staged fp32 via
//       dense global_load_lds with XOR bank-swizzle, 52KB LDS dbuf,
//       3 blocks/CU. ~182 us (proven floor of this structure; 5 structural
//       variants in rounds 11-14 all landed 181-235 us).
//   k2: GRU scan, 64 blocks x 8 waves, W_hh resident in regs (round 7).
//   k3: heads, 16 rows/block, 3200 blocks (32-row variant measured slower).
// ---------------------------------------------------------------------------

typedef __attribute__((ext_vector_type(8))) short   short8;
typedef __attribute__((ext_vector_type(8))) __bf16  bf16x8;
typedef __attribute__((ext_vector_type(4))) float   f32x4;

__device__ __forceinline__ float bf2f(unsigned short u) {
    unsigned int v = ((unsigned int)u) << 16;
    return __builtin_bit_cast(float, v);
}
__device__ __forceinline__ unsigned short f2bf(float f) {
    unsigned int v = __builtin_bit_cast(unsigned int, f);
    v = v + 0x7FFFu + ((v >> 16) & 1u);   // RNE
    return (unsigned short)(v >> 16);
}
__device__ __forceinline__ float softplusf(float x) {
    return (x > 20.f) ? x : log1pf(__expf(x));
}
__device__ __forceinline__ void gload_lds16(const void* g, void* l) {
    __builtin_amdgcn_global_load_lds(
        (const __attribute__((address_space(1))) void*)g,
        (__attribute__((address_space(3))) void*)l, 16, 0, 0);
}

// ---------------- workspace layout (bytes) ----------------
#define OFF_BPACK 81920000
#define OFF_WHH   83558400
#define OFF_WPQ1  83837952
#define OFF_WPQ2  84024320

// fragment mapping (mfma_f32_16x16x32_bf16):
//   A[l&15][(l>>4)*8+j], B[(l>>4)*8+j][l&15], D[(l>>4)*4+r][l&15]
// packed B storage: elem = ((kk*NT + nt)*64 + l)*8 + j

__global__ __launch_bounds__(256) void pack_kernel(
    const float* __restrict__ W_ih, const float* __restrict__ W_hh,
    const float* __restrict__ Wp1,  const float* __restrict__ Wq1,
    const float* __restrict__ Wp2,  const float* __restrict__ Wq2,
    unsigned short* __restrict__ Bpack, unsigned short* __restrict__ Whh_p,
    unsigned short* __restrict__ Wpq1,  unsigned short* __restrict__ Wpq2)
{
    int e = blockIdx.x * 256 + threadIdx.x;
    if (e < 819200) {                       // k1: K=1024(embed), N=800
        const int j = e & 7, l = (e >> 3) & 63;
        const int nt = (e >> 9) % 50, kk = e / (512 * 50);
        const int k = kk * 32 + (l >> 4) * 8 + j;
        const int c = nt * 16 + (l & 15);
        Bpack[e] = f2bf((c < 600) ? W_ih[(6 + k) * 600 + c]
                                  : Wq1[(200 + k) * 200 + (c - 600)]);
        return;
    }
    e -= 819200;
    if (e < 139776) {                       // W_hh: K pad 224, N = 3 gates x 13 tiles
        const int j = e & 7, l = (e >> 3) & 63;
        const int nt = (e >> 9) % 39, kk = e / (512 * 39);
        const int k = kk * 32 + (l >> 4) * 8 + j;
        const int g = nt / 13, st = nt % 13;
        const int c = st * 16 + (l & 15);
        Whh_p[e] = (k < 200 && c < 200) ? f2bf(W_hh[k * 600 + g * 200 + c]) : (unsigned short)0;
        return;
    }
    e -= 139776;
    if (e < 93184) {                        // heads1: [Wp1 | Wq1[:200]] K pad 224
        const int j = e & 7, l = (e >> 3) & 63;
        const int nt = (e >> 9) % 26, kk = e / (512 * 26);
        const int k = kk * 32 + (l >> 4) * 8 + j;
        unsigned short v = 0;
        if (nt < 13) { const int c = nt * 16 + (l & 15);        if (k < 200 && c < 200) v = f2bf(Wp1[k * 200 + c]); }
        else         { const int c = (nt - 13) * 16 + (l & 15); if (k < 200 && c < 200) v = f2bf(Wq1[k * 200 + c]); }
        Wpq1[e] = v;
        return;
    }
    e -= 93184;
    if (e < 28672) {                        // heads2: [Wp2 | Wq2] N pad 64 each
        const int j = e & 7, l = (e >> 3) & 63;
        const int nt = (e >> 9) % 8, kk = e / (512 * 8);
        const int k = kk * 32 + (l >> 4) * 8 + j;
        unsigned short v = 0;
        if (nt < 4) { const int c = nt * 16 + (l & 15);       if (k < 200 && c < 60) v = f2bf(Wp2[k * 60 + c]); }
        else        { const int c = (nt - 4) * 16 + (l & 15); if (k < 200 && c < 60) v = f2bf(Wq2[k * 60 + c]); }
        Wpq2[e] = v;
    }
}

// ---------------- kernel 1: GI/QE GEMM  M=51200 N=800 K=1024 ----------------
// grid 2000 = 400 M-chunks(128 rows) x 5 N-groups(160 cols = 10 tiles).
// 256 thr = 4 waves; wave w -> M-subtiles {2w,2w+1} x all 10 N-tiles.
// Buffer (bytes): [0,10240) B 10 tiles; [10240,26624) A 128 rows x 128B fp32,
// A region XOR-swizzled: LDS quad u of row r holds global quad u^(r&7).
// Staging source permuted to match (global_load_lds dest stays linear).
// Pipeline: issue(kk+1) -> vmcnt(Lw) -> bar -> compute -> lgkm(0) -> bar.
#define K1_BYTES 26624
__global__ __launch_bounds__(256, 3) void k1_gi(
    const float* __restrict__ embed,   // [51200][1024]
    const float* __restrict__ action,  // [51200][6]
    const float* __restrict__ W_ih,    // rows 0..5 = action part
    const float* __restrict__ b_ih,
    const float* __restrict__ bq1,
    const unsigned short* __restrict__ Bpack,
    unsigned short* __restrict__ GI)   // [51200][800] bf16
{
    __shared__ char bufS[2][K1_BYTES];

    const int tid = threadIdx.x;
    const int w = tid >> 6, l = tid & 63;
    const int lo = l & 15, hi = l >> 4;

    // XCD-bijective swizzle: 5 N-siblings of an M-chunk land on one XCD
    const int g    = (blockIdx.x & 7) * 250 + (blockIdx.x >> 3);
    const int mblk = g / 5;
    const int ng   = g - mblk * 5;
    const int rb   = mblk * 128;

    // ---- stage-chunk setup: 26 chunks, wave w does j = w + 4i  (w<2: 7, else 6)
    const char* sp[7]; int st[7]; int dof[7];
    const int nch = (w < 2) ? 7 : 6;
#pragma unroll
    for (int i = 0; i < 7; ++i) {
        int j = w + 4 * i; if (j >= 26) j = 25;
        if (j < 10) {                      // B tile j: 1KB linear from Bpack
            sp[i]  = (const char*)Bpack + (size_t)(ng * 10 + j) * 1024 + l * 16;
            st[i]  = 50 * 1024;            // bytes per kk
            dof[i] = j * 1024;
        } else {                           // A chunk: 8 rows x 128B, source
            const int a = j - 10;          // quad-permuted so LDS is swizzled
            sp[i]  = (const char*)embed
                   + (size_t)(rb + a * 8 + (l >> 3)) * 4096
                   + (((l & 7) ^ (l >> 3)) << 4);
            st[i]  = 128;                  // bytes per kk
            dof[i] = 10240 + a * 1024;
        }
    }

    f32x4 acc[2][10];
#pragma unroll
    for (int m = 0; m < 2; ++m)
#pragma unroll
        for (int i = 0; i < 10; ++i) acc[m][i] = f32x4{0.f, 0.f, 0.f, 0.f};

    // ---- prologue: issue stage kk=0 -> buf0 (no wait here)
#pragma unroll
    for (int i = 0; i < 7; ++i) if (i < nch) {
        gload_lds16(sp[i], &bufS[0][dof[i]]);
        sp[i] += st[i];
    }

    // ---- main loop
    int cur = 0;
    for (int kk = 0; kk < 32; ++kk) {
        const int nxt = cur ^ 1;
        if (kk < 31) {
#pragma unroll
            for (int i = 0; i < 7; ++i) if (i < nch) {
                gload_lds16(sp[i], &bufS[nxt][dof[i]]);
                sp[i] += st[i];
            }
            if (w < 2) asm volatile("s_waitcnt vmcnt(7)" ::: "memory");
            else       asm volatile("s_waitcnt vmcnt(6)" ::: "memory");
        } else {
            asm volatile("s_waitcnt vmcnt(0)" ::: "memory");
        }
        __builtin_amdgcn_s_barrier();          // buf cur fully staged, all waves
        __builtin_amdgcn_sched_barrier(0);

        // A fragments: swizzled read (bank-uniform) + fp32->bf16 convert
        const float* Af = (const float*)&bufS[cur][10240];
        bf16x8 af[2];
#pragma unroll
        for (int m = 0; m < 2; ++m) {
            const int row = (w * 2 + m) * 16 + lo;
            const int sw  = (row & 7) << 2;            // float-index XOR
            const float* base = Af + row * 32;
            f32x4 v0 = *(const f32x4*)(base + ((hi * 8) ^ sw));
            f32x4 v1 = *(const f32x4*)(base + ((hi * 8 + 4) ^ sw));
            bf16x8 t;
#pragma unroll
            for (int q = 0; q < 4; ++q) { t[q] = (__bf16)v0[q]; t[4 + q] = (__bf16)v1[q]; }
            af[m] = t;
        }
#pragma unroll
        for (int i = 0; i < 10; ++i) {
            bf16x8 b = __builtin_bit_cast(bf16x8,
                *(const short8*)&bufS[cur][i * 1024 + l * 16]);
            acc[0][i] = __builtin_amdgcn_mfma_f32_16x16x32_bf16(af[0], b, acc[0][i], 0, 0, 0);
            acc[1][i] = __builtin_amdgcn_mfma_f32_16x16x32_bf16(af[1], b, acc[1][i], 0, 0, 0);
        }

        asm volatile("s_waitcnt lgkmcnt(0)" ::: "memory");   // all LDS reads done
        __builtin_amdgcn_s_barrier();          // buf cur may be overwritten next
        __builtin_amdgcn_sched_barrier(0);
        cur = nxt;
    }

    // ---- epilogue: bias + action(K=6) contribution, store bf16
#pragma unroll
    for (int m = 0; m < 2; ++m) {
        const int rbase = rb + (w * 2 + m) * 16 + hi * 4;
        float av[4][6];
#pragma unroll
        for (int r = 0; r < 4; ++r)
#pragma unroll
            for (int k = 0; k < 6; ++k) av[r][k] = action[(size_t)(rbase + r) * 6 + k];
#pragma unroll
        for (int i = 0; i < 10; ++i) {
            const int col = ng * 160 + i * 16 + lo;
            const float bias = (col < 600) ? b_ih[col] : bq1[col - 600];
            float wa[6];
            if (col < 600) {
#pragma unroll
                for (int k = 0; k < 6; ++k) wa[k] = W_ih[k * 600 + col];
            }
#pragma unroll
            for (int r = 0; r < 4; ++r) {
                float v = acc[m][i][r] + bias;
                if (col < 600) {
#pragma unroll
                    for (int k = 0; k < 6; ++k) v += av[r][k] * wa[k];
                }
                GI[(size_t)(rbase + r) * 800 + col] = f2bf(v);
            }
        }
    }
}

// ---------------- kernel 2: GRU scan, 8 waves, resident weights ----------------
#define HSTRB 232   // hS row stride in bf16 elems (K pad >=224)
#define GSTR  227   // gAll row stride in floats (odd-ish vs 32 banks)

__global__ __launch_bounds__(512, 2) void k2_scan(
    unsigned short* __restrict__ GI,           // [51200][800] bf16 (deter -> cols 0..199)
    const unsigned short* __restrict__ Whh_p,
    const float* __restrict__ b_hh,
    float* __restrict__ out)                   // [51200][350] fp32 (cols 0..199 here)
{
    __shared__ unsigned short hS[16 * HSTRB];                 // 7424 B, bf16 h
    __shared__ float gAll[3 * 16 * GSTR];                     // 43584 B
    __shared__ __align__(16) unsigned short GIbuf[2][12288];  // 49152 B

    const int tid = threadIdx.x;
    const int w = tid >> 6, l = tid & 63;
    const int lo = l & 15, hi = l >> 4;
    const int r0 = blockIdx.x * 16;

    for (int i = tid; i < 16 * HSTRB; i += 512) hS[i] = 0;

    const int t0 = w * 5;
    const int ntl = (w == 7) ? 4 : 5;
    bf16x8 wf[5][7];
#pragma unroll
    for (int i = 0; i < 5; ++i)
#pragma unroll
        for (int kk = 0; kk < 7; ++kk)
            if (i < ntl)
                wf[i][kk] = __builtin_bit_cast(bf16x8,
                    *(const short8*)&Whh_p[((kk * 39 + (t0 + i)) * 64 + l) * 8]);

    int gOff[5];
#pragma unroll
    for (int i = 0; i < 5; ++i) {
        int nt = t0 + i; if (nt > 38) nt = 38;
        const int g = nt / 13, st = nt - g * 13;
        gOff[i] = (g * 16 + hi * 4) * GSTR + st * 16 + lo;
    }

    const char* srcB[3];
#pragma unroll
    for (int i = 0; i < 3; ++i) {
        int j = (i * 8 + w) * 64 + l;
        int rj = j / 75; int cj = j - rj * 75;
        if (rj > 15) { rj = 15; cj = 74; }
        srcB[i] = (const char*)GI + (size_t)(r0 + rj) * 50 * 1600 + (size_t)cj * 16;
    }

    const int c = tid & 255;
    const int rh = tid >> 8;
    const bool act = (c < 200);
    float bh0 = 0.f, bh1 = 0.f, bh2 = 0.f;
    if (act) { bh0 = b_hh[c]; bh1 = b_hh[200 + c]; bh2 = b_hh[400 + c]; }
    float h_reg[8] = {0.f, 0.f, 0.f, 0.f, 0.f, 0.f, 0.f, 0.f};

    {
#pragma unroll
        for (int i = 0; i < 3; ++i)
            gload_lds16(srcB[i], &GIbuf[0][(i * 8 + w) * 512]);
    }
    asm volatile("s_waitcnt lgkmcnt(0)" ::: "memory");
    __builtin_amdgcn_s_barrier();
    __builtin_amdgcn_sched_barrier(0);

    for (int t = 0; t < 50; ++t) {
        const int tn = (t < 49) ? t + 1 : 49;
        const int bsel = (t + 1) & 1;
#pragma unroll
        for (int i = 0; i < 3; ++i)
            gload_lds16(srcB[i] + (size_t)tn * 1600, &GIbuf[bsel][(i * 8 + w) * 512]);

        bf16x8 hf[7];
#pragma unroll
        for (int kk = 0; kk < 7; ++kk)
            hf[kk] = __builtin_bit_cast(bf16x8,
                *(const short8*)&hS[lo * HSTRB + kk * 32 + hi * 8]);
        f32x4 acc[5];
#pragma unroll
        for (int i = 0; i < 5; ++i) acc[i] = f32x4{0.f, 0.f, 0.f, 0.f};
#pragma unroll
        for (int i = 0; i < 5; ++i) if (i < ntl)
#pragma unroll
            for (int kk = 0; kk < 7; ++kk)
                acc[i] = __builtin_amdgcn_mfma_f32_16x16x32_bf16(hf[kk], wf[i][kk], acc[i], 0, 0, 0);

#pragma unroll
        for (int i = 0; i < 5; ++i) if (i < ntl)
#pragma unroll
            for (int r = 0; r < 4; ++r)
                gAll[gOff[i] + r * GSTR] = acc[i][r];

        asm volatile("s_waitcnt lgkmcnt(0)" ::: "memory");   // B1
        __builtin_amdgcn_s_barrier();
        __builtin_amdgcn_sched_barrier(0);
        asm volatile("s_waitcnt vmcnt(3)" ::: "memory");     // GIbuf[t&1] ready
        __builtin_amdgcn_sched_barrier(0);

        if (act) {
            const unsigned short* gib = &GIbuf[t & 1][0];
#pragma unroll
            for (int rr = 0; rr < 8; ++rr) {
                const int row = rh * 8 + rr;
                const float gi_r = bf2f(gib[row * 600 + c]);
                const float gi_z = bf2f(gib[row * 600 + 200 + c]);
                const float gi_n = bf2f(gib[row * 600 + 400 + c]);
                const float gr = gi_r + gAll[(0 * 16 + row) * GSTR + c] + bh0;
                const float gz = gi_z + gAll[(1 * 16 + row) * GSTR + c] + bh1;
                const float hn = gAll[(2 * 16 + row) * GSTR + c] + bh2;
                const float rs = __builtin_amdgcn_rcpf(1.f + __expf(-gr));
                const float zz = __builtin_amdgcn_rcpf(1.f + __expf(-gz));
                const float x  = gi_n + rs * hn;
                const float e2 = __expf(-2.f * fabsf(x));
                float th = (1.f - e2) * __builtin_amdgcn_rcpf(1.f + e2);
                th = __builtin_copysignf(th, x);
                const float h = (1.f - zz) * th + zz * h_reg[rr];
                h_reg[rr] = h;
                hS[row * HSTRB + c] = f2bf(h);
                const size_t bt = (size_t)((r0 + row) * 50 + t);
                out[bt * 350 + c] = h;                 // deter fp32
                GI[bt * 800 + c]  = f2bf(h);           // deter bf16 for k3
            }
        }

        asm volatile("s_waitcnt lgkmcnt(0)" ::: "memory");   // B2
        __builtin_amdgcn_s_barrier();
        __builtin_amdgcn_sched_barrier(0);
    }
}

// ---------------- kernel 3: heads, fully parallel over 51200 rows ----------------
__global__ __launch_bounds__(256, 1) void k3_heads(
    const unsigned short* __restrict__ GI,     // deter bf16 cols 0..199, QE cols 600..799
    const unsigned short* __restrict__ Wpq1,
    const unsigned short* __restrict__ Wpq2,
    const float* __restrict__ noise,           // [51200][30]
    const float* __restrict__ bp1,
    const float* __restrict__ bp2,
    const float* __restrict__ bq2,
    float* __restrict__ out)                   // cols 200..349
{
    __shared__ unsigned short pq[2][16 * HSTRB];
    __shared__ float ost[16 * 128];

    const int tid = threadIdx.x;
    const int w = tid >> 6, l = tid & 63;
    const int lo = l & 15, hi = l >> 4;
    const int r0 = blockIdx.x * 16;

    {   unsigned short* p0 = &pq[0][0];
        for (int i = tid; i < 2 * 16 * HSTRB; i += 256) p0[i] = 0; }
    __syncthreads();

    bf16x8 af[7];
#pragma unroll
    for (int kk = 0; kk < 7; ++kk)
        af[kk] = __builtin_bit_cast(bf16x8,
            *(const short8*)&GI[(size_t)(r0 + lo) * 800 + kk * 32 + hi * 8]);

    const int h1s = (w < 2) ? 7 * w : 14 + 6 * (w - 2);
    const int h1n = (w < 2) ? 7 : 6;
    f32x4 a2[7];
#pragma unroll
    for (int i = 0; i < 7; ++i) a2[i] = f32x4{0.f, 0.f, 0.f, 0.f};
#pragma unroll
    for (int i = 0; i < 7; ++i) if (i < h1n) {
        const int nt = h1s + i;
#pragma unroll
        for (int kk = 0; kk < 7; ++kk) {
            bf16x8 b = __builtin_bit_cast(bf16x8,
                *(const short8*)&Wpq1[((kk * 26 + nt) * 64 + l) * 8]);
            a2[i] = __builtin_amdgcn_mfma_f32_16x16x32_bf16(af[kk], b, a2[i], 0, 0, 0);
        }
    }
#pragma unroll
    for (int i = 0; i < 7; ++i) if (i < h1n) {
        const int nt = h1s + i;
        const bool isq = (nt >= 13);
        const int c1 = (isq ? (nt - 13) : nt) * 16 + lo;
        if (c1 < 200) {
#pragma unroll
            for (int r = 0; r < 4; ++r) {
                const int row = hi * 4 + r;
                float v = a2[i][r];
                if (isq) v += bf2f(GI[(size_t)(r0 + row) * 800 + 600 + c1]);  // QE (incl bq1)
                else     v += bp1[c1];
                v = (v > 0.f) ? v : expm1f(v);                                 // ELU
                pq[isq ? 1 : 0][row * HSTRB + c1] = f2bf(v);
            }
        }
    }
    __syncthreads();

    const unsigned short* srcS = &pq[(w >= 2) ? 1 : 0][0];
    bf16x8 pf[7];
#pragma unroll
    for (int kk = 0; kk < 7; ++kk)
        pf[kk] = __builtin_bit_cast(bf16x8,
            *(const short8*)&srcS[lo * HSTRB + kk * 32 + hi * 8]);
    f32x4 a3[2];
    a3[0] = f32x4{0.f, 0.f, 0.f, 0.f};
    a3[1] = f32x4{0.f, 0.f, 0.f, 0.f};
#pragma unroll
    for (int i = 0; i < 2; ++i) {
        const int nt = ((w >= 2) ? 4 : 0) + (w & 1) * 2 + i;
#pragma unroll
        for (int kk = 0; kk < 7; ++kk) {
            bf16x8 b = __builtin_bit_cast(bf16x8,
                *(const short8*)&Wpq2[((kk * 8 + nt) * 64 + l) * 8]);
            a3[i] = __builtin_amdgcn_mfma_f32_16x16x32_bf16(pf[kk], b, a3[i], 0, 0, 0);
        }
    }
#pragma unroll
    for (int i = 0; i < 2; ++i) {
        const int nt = ((w >= 2) ? 4 : 0) + (w & 1) * 2 + i;
        const int cl = (nt & 3) * 16 + lo;
        if (cl < 60) {
            const float bb = (nt < 4) ? bp2[cl] : bq2[cl];
            const int obase = ((nt < 4) ? 0 : 64) + ((cl < 30) ? cl : (32 + cl - 30));
#pragma unroll
            for (int r = 0; r < 4; ++r)
                ost[(hi * 4 + r) * 128 + obase] = a3[i][r] + bb;
        }
    }
    __syncthreads();

    for (int idx = tid; idx < 16 * 150; idx += 256) {
        const int row = idx / 150;
        const int c = 200 + (idx - row * 150);
        const size_t bt = (size_t)(r0 + row);
        const float* o = &ost[row * 128];
        float v;
        if (c < 230) {
            const int j = c - 200;
            const float qs = softplusf(o[96 + j]) + 0.1f;
            v = o[64 + j] + qs * noise[bt * 30 + j];
        }
        else if (c < 260) v = o[c - 230];
        else if (c < 290) v = softplusf(o[32 + (c - 260)]) + 0.1f;
        else if (c < 320) v = o[64 + (c - 290)];
        else              v = softplusf(o[96 + (c - 320)]) + 0.1f;
        out[bt * 350 + c] = v;
    }
}

// ---------------------------------------------------------------------------
extern "C" void kernel_launch(void* const* d_in, const int* in_sizes, int n_in,
                              void* d_out, int out_size, void* d_ws, size_t ws_size,
                              hipStream_t stream)
{
    const float* action = (const float*)d_in[0];
    const float* embed  = (const float*)d_in[1];
    const float* noise  = (const float*)d_in[2];
    const float* W_ih   = (const float*)d_in[3];
    const float* W_hh   = (const float*)d_in[4];
    const float* b_ih   = (const float*)d_in[5];
    const float* b_hh   = (const float*)d_in[6];
    const float* Wp1    = (const float*)d_in[7];
    const float* bp1    = (const float*)d_in[8];
    const float* Wp2    = (const float*)d_in[9];
    const float* bp2    = (const float*)d_in[10];
    const float* Wq1    = (const float*)d_in[11];
    const float* bq1    = (const float*)d_in[12];
    const float* Wq2    = (const float*)d_in[13];
    const float* bq2    = (const float*)d_in[14];
    (void)in_sizes; (void)n_in; (void)out_size; (void)ws_size;

    char* ws = (char*)d_ws;
    unsigned short* GI    = (unsigned short*)(ws);
    unsigned short* Bpack = (unsigned short*)(ws + OFF_BPACK);
    unsigned short* Whh_p = (unsigned short*)(ws + OFF_WHH);
    unsigned short* Wpq1  = (unsigned short*)(ws + OFF_WPQ1);
    unsigned short* Wpq2  = (unsigned short*)(ws + OFF_WPQ2);
    float* outp = (float*)d_out;

    pack_kernel<<<4222, 256, 0, stream>>>(W_ih, W_hh, Wp1, Wq1, Wp2, Wq2,
                                          Bpack, Whh_p, Wpq1, Wpq2);
    k1_gi<<<2000, 256, 0, stream>>>(embed, action, W_ih, b_ih, bq1, Bpack, GI);
    k2_scan<<<64, 512, 0, stream>>>(GI, Whh_p, b_hh, outp);
    k3_heads<<<3200, 256, 0, stream>>>(GI, Wpq1, Wpq2, noise, bp1, bp2, bq2, outp);
}